// Round 2
// baseline (345.346 us; speedup 1.0000x reference)
//
#include <hip/hip_runtime.h>
#include <math.h>

// Problem constants (fixed by reference: B=32,T=1024,D=256,K=1024)
#define N_ROWS 32768
#define DIM    256
#define KCODES 1024

#define BM 128   // rows per block
#define BK 256   // codes per k-tile (loop 4x for full K)
#define BD 32    // d-chunk staged in LDS
#define AST 36   // padded stride
#define BST 36

// ---------------------------------------------------------------------------
// Exact replica of numpy pairwise sum of squares for n=256 rows:
//   block(128): r[j]=a[j]; for m=1..15: r[j]+=a[8m+j];
//               res = ((r0+r1)+(r2+r3))+((r4+r5)+(r6+r7))
//   total = block(a[0:128]) + block(a[128:256])
// Squares are materialized (rounded fp32 mul) before summing, like emb*emb.
// One wave per row; 4 rows per 256-thread block.
__global__ __launch_bounds__(256) void rowsum_sq_kernel(const float* __restrict__ src,
                                                        float* __restrict__ dst,
                                                        int nrows) {
    __shared__ float sq[4][260];   // padded: (4*row + j) bank spread
    const int wave = threadIdx.x >> 6;
    const int lane = threadIdx.x & 63;
    const int row  = blockIdx.x * 4 + wave;
    if (row >= nrows) return;

    const float4* rp = (const float4*)(src + (size_t)row * DIM);
    float4 v = rp[lane];
    // materialize squares (separate rounding step — must NOT fuse into fma)
    sq[wave][lane * 4 + 0] = v.x * v.x;
    sq[wave][lane * 4 + 1] = v.y * v.y;
    sq[wave][lane * 4 + 2] = v.z * v.z;
    sq[wave][lane * 4 + 3] = v.w * v.w;
    // same-wave LDS write->read: compiler inserts lgkmcnt wait; no barrier needed
    if (lane < 8) {
#pragma clang fp contract(off)
        const int j = lane;
        float rA = sq[wave][j];
#pragma unroll
        for (int m = 1; m < 16; ++m) rA += sq[wave][8 * m + j];
        float rB = sq[wave][128 + j];
#pragma unroll
        for (int m = 1; m < 16; ++m) rB += sq[wave][128 + 8 * m + j];
        // combine tree ((r0+r1)+(r2+r3))+((r4+r5)+(r6+r7)) via butterflies
        rA = rA + __shfl_xor(rA, 1, 64);
        rA = rA + __shfl_xor(rA, 2, 64);
        rA = rA + __shfl_xor(rA, 4, 64);
        rB = rB + __shfl_xor(rB, 1, 64);
        rB = rB + __shfl_xor(rB, 2, 64);
        rB = rB + __shfl_xor(rB, 4, 64);
        if (j == 0) dst[row] = rA + rB;
    }
}

// ---------------------------------------------------------------------------
// Fused: scores = (e2[k] - 2 * X @ E^T) + x2[row], per-row argmin (lowest-index
// tie-break, matching np.argmin over fp32 values), gather + write outputs.
// Block: 512 threads = 16 ty (row groups) x 32 tx (code groups).
// Thread micro-tile: 8 rows (ty + 16*i) x 8 codes (tx + 32*j).
// Dot accumulation: single fp32 FMA accumulator, d ascending 0..255 — matches
// BLAS sgemm microkernel accumulation order.
__global__ __launch_bounds__(512) void vq_kernel(const float* __restrict__ X,
                                                 const float* __restrict__ E,
                                                 const float* __restrict__ e2g,
                                                 const float* __restrict__ x2g,
                                                 float* __restrict__ out0,
                                                 float* __restrict__ out1,
                                                 float* __restrict__ out2) {
    __shared__ float a_tile[BM][AST];   // 18432 B
    __shared__ float b_tile[BK][BST];   // 36864 B
    __shared__ int   idx_lds[BM];       // 512 B

    const int tid  = threadIdx.x;
    const int tx   = tid & 31;   // code group
    const int ty   = tid >> 5;   // row group (0..15)
    const int row0 = blockIdx.x * BM;

    float x2r[8];
#pragma unroll
    for (int i = 0; i < 8; ++i) x2r[i] = x2g[row0 + ty + 16 * i];

    float runval[8];
    int   runidx[8];
#pragma unroll
    for (int i = 0; i < 8; ++i) { runval[i] = INFINITY; runidx[i] = 0; }

    for (int kt = 0; kt < KCODES / BK; ++kt) {
        float acc[8][8];
#pragma unroll
        for (int i = 0; i < 8; ++i)
#pragma unroll
            for (int j = 0; j < 8; ++j) acc[i][j] = 0.f;

        float e2r[8];
#pragma unroll
        for (int j = 0; j < 8; ++j) e2r[j] = e2g[kt * BK + tx + 32 * j];

        for (int dc = 0; dc < DIM / BD; ++dc) {
            __syncthreads();
            // stage A tile: 128 rows x 32 d = 1024 float4, 2 per thread
#pragma unroll
            for (int s = 0; s < 2; ++s) {
                int q = tid + s * 512;
                int r = q >> 3, g = q & 7;
                float4 v = *(const float4*)(X + (size_t)(row0 + r) * DIM + dc * BD + g * 4);
                *(float4*)(&a_tile[r][g * 4]) = v;
            }
            // stage B tile: 256 codes x 32 d = 2048 float4, 4 per thread
#pragma unroll
            for (int s = 0; s < 4; ++s) {
                int q = tid + s * 512;
                int r = q >> 3, g = q & 7;
                float4 v = *(const float4*)(E + (size_t)(kt * BK + r) * DIM + dc * BD + g * 4);
                *(float4*)(&b_tile[r][g * 4]) = v;
            }
            __syncthreads();
#pragma unroll
            for (int dd = 0; dd < BD; dd += 4) {
                float4 af[8], bf[8];
#pragma unroll
                for (int i = 0; i < 8; ++i)
                    af[i] = *(const float4*)(&a_tile[ty + 16 * i][dd]);
#pragma unroll
                for (int j = 0; j < 8; ++j)
                    bf[j] = *(const float4*)(&b_tile[tx + 32 * j][dd]);
#pragma unroll
                for (int i = 0; i < 8; ++i)
#pragma unroll
                    for (int j = 0; j < 8; ++j) {
                        acc[i][j] = fmaf(af[i].x, bf[j].x, acc[i][j]);
                        acc[i][j] = fmaf(af[i].y, bf[j].y, acc[i][j]);
                        acc[i][j] = fmaf(af[i].z, bf[j].z, acc[i][j]);
                        acc[i][j] = fmaf(af[i].w, bf[j].w, acc[i][j]);
                    }
            }
        }
        // fold into running argmin. Score mimics numpy elementwise rounding:
        //   t1 = fp32(e2 - 2*dot); s = fp32(t1 + x2)
        // k ascending + strict < preserves lowest-index-wins tie semantics.
#pragma unroll
        for (int i = 0; i < 8; ++i)
#pragma unroll
            for (int j = 0; j < 8; ++j) {
                float t1 = e2r[j] - 2.0f * acc[i][j];
                float s  = t1 + x2r[i];
                int kg = kt * BK + tx + 32 * j;
                if (s < runval[i]) { runval[i] = s; runidx[i] = kg; }
            }
    }

    // butterfly argmin-reduce across the 32 tx lanes (ties -> lowest index)
#pragma unroll
    for (int i = 0; i < 8; ++i) {
        float v  = runval[i];
        int   ix = runidx[i];
#pragma unroll
        for (int off = 16; off > 0; off >>= 1) {
            float ov = __shfl_xor(v, off, 64);
            int   oi = __shfl_xor(ix, off, 64);
            if (ov < v || (ov == v && oi < ix)) { v = ov; ix = oi; }
        }
        if (tx == 0) idx_lds[ty + 16 * i] = ix;
    }
    __syncthreads();

    // epilogue: indices (as float) + gather embedding rows to both outputs
    if (tid < BM) out2[row0 + tid] = (float)idx_lds[tid];
#pragma unroll
    for (int it = 0; it < (BM * (DIM / 4)) / 512; ++it) {   // 16 iters
        int f = tid + it * 512;
        int r = f >> 6;   // row within tile
        int p = f & 63;   // float4 position
        int ix = idx_lds[r];
        float4 v = *(const float4*)(E + (size_t)ix * DIM + p * 4);
        size_t o = (size_t)(row0 + r) * DIM + (size_t)p * 4;
        *(float4*)(out0 + o) = v;
        *(float4*)(out1 + o) = v;
    }
}

// ---------------------------------------------------------------------------
extern "C" void kernel_launch(void* const* d_in, const int* in_sizes, int n_in,
                              void* d_out, int out_size, void* d_ws, size_t ws_size,
                              hipStream_t stream) {
    const float* X = (const float*)d_in[0];
    const float* E = (const float*)d_in[1];
    float* e2   = (float*)d_ws;                    // KCODES floats
    float* x2   = e2 + KCODES;                     // N_ROWS floats
    float* out0 = (float*)d_out;                   // embed_idx   [N, D]
    float* out1 = out0 + (size_t)N_ROWS * DIM;     // embed_idx_qx[N, D]
    float* out2 = out1 + (size_t)N_ROWS * DIM;     // quantized_idx as float [N]

    rowsum_sq_kernel<<<dim3(KCODES / 4), dim3(256), 0, stream>>>(E, e2, KCODES);
    rowsum_sq_kernel<<<dim3(N_ROWS / 4), dim3(256), 0, stream>>>(X, x2, N_ROWS);
    vq_kernel<<<dim3(N_ROWS / BM), dim3(512), 0, stream>>>(X, E, e2, x2,
                                                           out0, out1, out2);
}